// Round 1
// baseline (1226.021 us; speedup 1.0000x reference)
//
#include <hip/hip_runtime.h>

#define HH 64
#define WW 64
#define HO 62
#define WO 62
#define NV 8          // N_CONVS
#define NF 9          // features per pixel: silu + 8 spline bases
#define KK 9          // 3x3 taps
#define TILE_Y 16
#define IN_ROWS 18    // TILE_Y + 2

// block = 256 threads; grid = (B*C planes = 256, y-tiles = 4)
// Each thread owns one column (tx 0..63, masked >=62) and 4 rows (ty+4p).
__global__ __launch_bounds__(256) void kan_conv_kernel(
    const float* __restrict__ x,     // (B,C,64,64)
    const float* __restrict__ grid,  // (9,12) rows identical
    const float* __restrict__ bw,    // (8,9)
    const float* __restrict__ sw,    // (8,9,8)
    const float* __restrict__ sc,    // (8,9)
    float* __restrict__ out)         // (B, C*8, 62, 62)
{
    __shared__ float feat[IN_ROWS * WW * NF];  // 18*64*9*4B = 41.5 KB
    __shared__ float wts[KK * NF * NV];        // 648 floats, [k][f][v]

    const int tid   = threadIdx.x;
    const int plane = blockIdx.x;              // b*C + c
    const int oy    = blockIdx.y * TILE_Y;

    // ---- fold weights into LDS: f==0 -> base_weight, f>=1 -> spline_weight*scaler
    for (int i = tid; i < KK * NF * NV; i += 256) {
        int v = i & 7;
        int f = (i >> 3) % 9;
        int k = i / 72;
        float w;
        if (f == 0) w = bw[v * 9 + k];
        else        w = sw[(v * 9 + k) * 8 + (f - 1)] * sc[v * 9 + k];
        wts[i] = w;
    }

    // ---- grid knots + reciprocal spans (per thread, hoisted divisions)
    float g[12];
    #pragma unroll
    for (int i = 0; i < 12; ++i) g[i] = grid[i];   // row 0 (all rows identical)
    float r1[11], r2[10], r3[9];
    #pragma unroll
    for (int i = 0; i < 11; ++i) r1[i] = 1.0f / (g[i + 1] - g[i]);
    #pragma unroll
    for (int i = 0; i < 10; ++i) r2[i] = 1.0f / (g[i + 2] - g[i]);
    #pragma unroll
    for (int i = 0; i < 9;  ++i) r3[i] = 1.0f / (g[i + 3] - g[i]);

    const float* xp = x + (size_t)plane * (HH * WW);

    // ---- stage 1: per-input-pixel features (computed ONCE, not 9x)
    for (int idx = tid; idx < IN_ROWS * WW; idx += 256) {
        const int iy = idx >> 6;        // 0..17
        const int ix = idx & 63;        // 0..63
        const int gy = oy + iy;
        const float xv = (gy < HH) ? xp[gy * WW + ix] : 0.0f;

        // silu
        const float s = xv / (1.0f + __expf(-xv));

        // Cox-de Boor, order 3 (identical recursion to reference)
        float b0[11];
        #pragma unroll
        for (int i = 0; i < 11; ++i)
            b0[i] = (xv >= g[i] && xv < g[i + 1]) ? 1.0f : 0.0f;
        float b1[10];
        #pragma unroll
        for (int i = 0; i < 10; ++i)
            b1[i] = (xv - g[i]) * r1[i] * b0[i] + (g[i + 2] - xv) * r1[i + 1] * b0[i + 1];
        float b2[9];
        #pragma unroll
        for (int i = 0; i < 9; ++i)
            b2[i] = (xv - g[i]) * r2[i] * b1[i] + (g[i + 3] - xv) * r2[i + 1] * b1[i + 1];
        float b3[8];
        #pragma unroll
        for (int i = 0; i < 8; ++i)
            b3[i] = (xv - g[i]) * r3[i] * b2[i] + (g[i + 4] - xv) * r3[i + 1] * b2[i + 1];

        float* fp = &feat[idx * NF];
        fp[0] = s;
        #pragma unroll
        for (int j = 0; j < 8; ++j) fp[1 + j] = b3[j];
    }
    __syncthreads();

    // ---- stage 2: 3x3 conv over 9 features -> 8 outputs, 4 pixels/thread
    const int tx = tid & 63;   // column
    const int ty = tid >> 6;   // 0..3 (rows ty, ty+4, ty+8, ty+12)
    if (tx >= WO) return;

    float acc[4][NV];
    #pragma unroll
    for (int p = 0; p < 4; ++p)
        #pragma unroll
        for (int v = 0; v < NV; ++v) acc[p][v] = 0.0f;

    #pragma unroll
    for (int ki = 0; ki < 3; ++ki) {
        #pragma unroll
        for (int kj = 0; kj < 3; ++kj) {
            const int k = ki * 3 + kj;
            #pragma unroll
            for (int f = 0; f < NF; ++f) {
                const float4 w0 = *reinterpret_cast<const float4*>(&wts[(k * NF + f) * NV]);
                const float4 w1 = *reinterpret_cast<const float4*>(&wts[(k * NF + f) * NV + 4]);
                #pragma unroll
                for (int p = 0; p < 4; ++p) {
                    const int iy = ty + 4 * p + ki;            // 0..17
                    const float fv = feat[((iy << 6) + tx + kj) * NF + f];
                    acc[p][0] += fv * w0.x;
                    acc[p][1] += fv * w0.y;
                    acc[p][2] += fv * w0.z;
                    acc[p][3] += fv * w0.w;
                    acc[p][4] += fv * w1.x;
                    acc[p][5] += fv * w1.y;
                    acc[p][6] += fv * w1.z;
                    acc[p][7] += fv * w1.w;
                }
            }
        }
    }

    // ---- store: out[((plane*8 + v)*HO + ho)*WO + wo]
    #pragma unroll
    for (int p = 0; p < 4; ++p) {
        const int ho = oy + ty + 4 * p;
        if (ho < HO) {
            #pragma unroll
            for (int v = 0; v < NV; ++v) {
                out[((size_t)(plane * NV + v) * HO + ho) * WO + tx] = acc[p][v];
            }
        }
    }
}

extern "C" void kernel_launch(void* const* d_in, const int* in_sizes, int n_in,
                              void* d_out, int out_size, void* d_ws, size_t ws_size,
                              hipStream_t stream) {
    const float* x    = (const float*)d_in[0];
    const float* grid = (const float*)d_in[1];
    const float* bw   = (const float*)d_in[2];
    const float* sw   = (const float*)d_in[3];
    const float* sc   = (const float*)d_in[4];
    float* out = (float*)d_out;

    dim3 grid_dim(256, 4);   // 256 (b,c) planes x 4 y-tiles
    kan_conv_kernel<<<grid_dim, 256, 0, stream>>>(x, grid, bw, sw, sc, out);
}